// Round 1
// 172.570 us; speedup vs baseline: 1.0329x; 1.0329x over previous
//
#include <hip/hip_runtime.h>

#define NN 2048
#define MLPW 16

typedef __attribute__((ext_vector_type(8))) short short8v;
typedef __attribute__((ext_vector_type(16))) float float16v;
typedef __attribute__((ext_vector_type(4))) unsigned short ushort4v;
typedef __attribute__((ext_vector_type(8))) unsigned short ushort8v;

__device__ __forceinline__ unsigned short f2b(float f) {
  unsigned int u = __float_as_uint(f);
  unsigned int r = (u + 0x7fffu + ((u >> 16) & 1u)) >> 16;  // RNE
  return (unsigned short)r;
}
__device__ __forceinline__ float b2f(unsigned short u) {
  return __uint_as_float(((unsigned int)u) << 16);
}

// ---------------- K1: edge MLP -> Abf16 (unnormalized, +I), dr ---------------
__global__ void __launch_bounds__(256) edge_kernel(
    const float* __restrict__ adj, const float* __restrict__ xdeg,
    const float* __restrict__ ydeg,
    const float* __restrict__ Wm1, const float* __restrict__ bm1,
    const float* __restrict__ Wm2, const float* __restrict__ bm2,
    unsigned short* __restrict__ Abf, float* __restrict__ dr) {
  __shared__ float w1[48], b1[16], w2[32], b2s[2];
  __shared__ float wsum[4];
  const int tid = threadIdx.x;
  if (tid < 48) w1[tid] = Wm1[tid];
  if (tid < 16) b1[tid] = bm1[tid];
  if (tid < 32) w2[tid] = Wm2[tid];
  if (tid < 2) b2s[tid] = bm2[tid];
  __syncthreads();
  const int i = blockIdx.x;
  const float4* adj4 = (const float4*)(adj + (size_t)i * NN);
  const float4* xd4 = (const float4*)(xdeg + (size_t)i * NN);
  const float4* yd4 = (const float4*)(ydeg + (size_t)i * NN);
  ushort4v* A4 = (ushort4v*)(Abf + (size_t)i * NN);
  float rsum = 0.f;
  for (int j4 = tid; j4 < NN / 4; j4 += 256) {
    float4 av = adj4[j4], xv = xd4[j4], yv = yd4[j4];
    float aa[4] = {av.x, av.y, av.z, av.w};
    float xx[4] = {xv.x, xv.y, xv.z, xv.w};
    float yy[4] = {yv.x, yv.y, yv.z, yv.w};
    ushort4v oo;
#pragma unroll
    for (int e = 0; e < 4; e++) {
      float l0 = b2s[0], l1 = b2s[1];
#pragma unroll
      for (int k = 0; k < MLPW; k++) {
        float h = fmaf(aa[e], w1[k], fmaf(xx[e], w1[16 + k], fmaf(yy[e], w1[32 + k], b1[k])));
        h = fmaxf(h, 0.f);
        l0 = fmaf(h, w2[2 * k], l0);
        l1 = fmaf(h, w2[2 * k + 1], l1);
      }
      float mask = 1.f / (1.f + __expf(l0 - l1));  // softmax[...,1]
      float v = aa[e] * mask;
      int j = j4 * 4 + e;
      if (j == i) v += 1.f;
      oo[e] = f2b(v);
      rsum += v;
    }
    A4[j4] = oo;
  }
#pragma unroll
  for (int off = 32; off > 0; off >>= 1) rsum += __shfl_down(rsum, off);
  if ((tid & 63) == 0) wsum[tid >> 6] = rsum;
  __syncthreads();
  if (tid == 0) {
    float t = wsum[0] + wsum[1] + wsum[2] + wsum[3];
    dr[i] = t > 0.f ? rsqrtf(t) : 0.f;
  }
}

// ---------------- K2 (fused aux): colsum partials + x->bf16 + Wg1^T->bf16 ----
// blocks [0,256): colsum of 8 Abf rows each -> partial[256][2048]
// blocks [256,1280): cast x fp32 -> xb bf16 (2048 elems/block)
// blocks [1280,1408): transpose+cast Wg1 [1024][256] -> Wg1T bf16 [256][1024]
__global__ void __launch_bounds__(256) aux_kernel(
    const unsigned short* __restrict__ Abf, const float* __restrict__ x,
    const float* __restrict__ Wg1, float* __restrict__ partial,
    unsigned short* __restrict__ xb, unsigned short* __restrict__ Wg1T) {
  const int b = blockIdx.x, tid = threadIdx.x;
  if (b < 256) {
    const int j0 = tid * 8, i0 = b * 8;
    float s[8] = {0, 0, 0, 0, 0, 0, 0, 0};
#pragma unroll
    for (int i = 0; i < 8; i++) {
      ushort8v a = *(const ushort8v*)&Abf[(size_t)(i0 + i) * NN + j0];
#pragma unroll
      for (int e = 0; e < 8; e++) s[e] += b2f(a[e]);
    }
    float* p = partial + (size_t)b * NN + j0;
    *(float4*)p = make_float4(s[0], s[1], s[2], s[3]);
    *(float4*)(p + 4) = make_float4(s[4], s[5], s[6], s[7]);
  } else if (b < 1280) {
    const size_t idx = (size_t)(b - 256) * 2048 + (size_t)tid * 8;
    const float4 u = *(const float4*)&x[idx], v = *(const float4*)&x[idx + 4];
    ushort8v o = {f2b(u.x), f2b(u.y), f2b(u.z), f2b(u.w),
                  f2b(v.x), f2b(v.y), f2b(v.z), f2b(v.w)};
    *(ushort8v*)&xb[idx] = o;
  } else {
    const int bo = b - 1280;
    const int n = bo * 2 + (tid >> 7);
    const int k0 = (tid & 127) * 8;
    ushort8v o;
#pragma unroll
    for (int e = 0; e < 8; e++) o[e] = f2b(Wg1[(size_t)(k0 + e) * 256 + n]);
    *(ushort8v*)&Wg1T[(size_t)n * 1024 + k0] = o;
  }
}

// ---------------- K3: dc = rsqrt(colsum) -------------------------------------
// grid 64: block handles 32 cols; 8 groups of 32 partial-rows each, LDS reduce.
__global__ void __launch_bounds__(256) dc_kernel(
    const float* __restrict__ partial, float* __restrict__ dc) {
  __shared__ float red[8][32];
  const int l = threadIdx.x & 31, g = threadIdx.x >> 5;
  const int col = blockIdx.x * 32 + l;
  float s = 0.f;
#pragma unroll
  for (int q = 0; q < 32; q++) s += partial[(size_t)(g * 32 + q) * NN + col];
  red[g][l] = s;
  __syncthreads();
  if (g == 0) {
    float t = s;
#pragma unroll
    for (int gg = 1; gg < 8; gg++) t += red[gg][l];
    dc[col] = t > 0.f ? rsqrtf(t) : 0.f;
  }
}

// ---------------- split-K MFMA GEMM (bf16 x bf16) ----------------------------
// P[sk][m][n] = sum_{k in chunk} A[m][k]*B[n][k].  BM=64 x BN=128, KC=128.
// 4 waves: wave w -> rows (w&1)*32, cols (w>>1)*64 (2 n-tiles, acc[2][16]).
// LDS stride 136 ushorts (68 dw == 4 mod 32): frag reads 4-way conflict max.
__global__ void __launch_bounds__(256) gemm_splitk_kernel(
    const unsigned short* __restrict__ A, const unsigned short* __restrict__ B,
    float* __restrict__ P, int M, int N, int K, int Kc) {
  constexpr int SW = 136;
  __shared__ unsigned short As[64 * SW];
  __shared__ unsigned short Bs[128 * SW];
  const int tid = threadIdx.x;
  const int lane = tid & 63, wave = tid >> 6;
  const int l31 = lane & 31, half = lane >> 5;
  const int mh = wave & 1, nh = wave >> 1;
  const int row0 = blockIdx.y * 64, col0 = blockIdx.x * 128;
  const int kbeg = blockIdx.z * Kc;

  float16v acc0, acc1;
#pragma unroll
  for (int r = 0; r < 16; r++) { acc0[r] = 0.f; acc1[r] = 0.f; }

  for (int k0 = 0; k0 < Kc; k0 += 128) {
    // stage A: 64 rows x 128 k = 1024 chunks, 4/thread
#pragma unroll
    for (int i = 0; i < 4; i++) {
      const int id = tid + i * 256;
      const int r = id >> 4, c = id & 15;
      *(ushort8v*)&As[r * SW + c * 8] =
          *(const ushort8v*)&A[(size_t)(row0 + r) * K + kbeg + k0 + c * 8];
    }
    // stage B: 128 rows x 128 k = 2048 chunks, 8/thread
#pragma unroll
    for (int i = 0; i < 8; i++) {
      const int id = tid + i * 256;
      const int r = id >> 4, c = id & 15;
      *(ushort8v*)&Bs[r * SW + c * 8] =
          *(const ushort8v*)&B[(size_t)(col0 + r) * K + kbeg + k0 + c * 8];
    }
    __syncthreads();
#pragma unroll
    for (int ks = 0; ks < 8; ks++) {
      short8v a = *(const short8v*)&As[(mh * 32 + l31) * SW + ks * 16 + half * 8];
      short8v b0 = *(const short8v*)&Bs[(nh * 64 + l31) * SW + ks * 16 + half * 8];
      short8v b1 = *(const short8v*)&Bs[(nh * 64 + 32 + l31) * SW + ks * 16 + half * 8];
      acc0 = __builtin_amdgcn_mfma_f32_32x32x16_bf16(a, b0, acc0, 0, 0, 0);
      acc1 = __builtin_amdgcn_mfma_f32_32x32x16_bf16(a, b1, acc1, 0, 0, 0);
    }
    __syncthreads();
  }
  // C/D: col = lane&31, row = (reg&3) + 8*(reg>>2) + 4*(lane>>5)
  float* Pb = P + ((size_t)blockIdx.z * M + row0 + mh * 32) * N + col0 + nh * 64 + l31;
#pragma unroll
  for (int reg = 0; reg < 16; reg++) {
    const int m = (reg & 3) + 8 * (reg >> 2) + 4 * half;
    Pb[(size_t)m * N] = acc0[reg];
    Pb[(size_t)m * N + 32] = acc1[reg];
  }
}

// ---------------- reduce GEMM1 partials -> XWT bf16 [256][2048], *dc[col] ----
__global__ void __launch_bounds__(256) reduce_xwt_kernel(
    const float* __restrict__ P, const float* __restrict__ dc,
    unsigned short* __restrict__ XWT) {
  const int t = blockIdx.x * 256 + threadIdx.x;
  const int i = t >> 8;            // output row (0..255)
  const int j0 = (t & 255) * 8;    // output col group
  float s[8] = {0, 0, 0, 0, 0, 0, 0, 0};
#pragma unroll
  for (int sk = 0; sk < 8; sk++) {
    const float* p = P + ((size_t)sk * 256 + i) * 2048 + j0;
    float4 u = *(const float4*)p, v = *(const float4*)(p + 4);
    s[0] += u.x; s[1] += u.y; s[2] += u.z; s[3] += u.w;
    s[4] += v.x; s[5] += v.y; s[6] += v.z; s[7] += v.w;
  }
  float4 d0 = *(const float4*)&dc[j0], d1 = *(const float4*)&dc[j0 + 4];
  ushort8v o = {f2b(s[0] * d0.x), f2b(s[1] * d0.y), f2b(s[2] * d0.z), f2b(s[3] * d0.w),
                f2b(s[4] * d1.x), f2b(s[5] * d1.y), f2b(s[6] * d1.z), f2b(s[7] * d1.w)};
  *(ushort8v*)&XWT[(size_t)i * 2048 + j0] = o;
}

// ---------------- fused tail: P2 -> T1(=dr*sum) -> hid(@Wl2+bl2) -> HW -------
// grid 256 blocks, 8 rows each.
__global__ void __launch_bounds__(256) tail_kernel(
    const float* __restrict__ P2, const float* __restrict__ dr,
    const float* __restrict__ dc, const float* __restrict__ Wl2,
    const float* __restrict__ bl2, const float* __restrict__ Wg2,
    float* __restrict__ hid, float* __restrict__ HW) {
  __shared__ float T1s[8][256];
  __shared__ float hidS[8][68];
  const int m0 = blockIdx.x * 8;
  const int tid = threadIdx.x;
  // phase 1: reduce 8 split-K partials, scale by dr
#pragma unroll
  for (int i = 0; i < 8; i++) {
    const int idx = tid + i * 256;
    const int mi = idx >> 8, n = idx & 255;
    float s = 0.f;
#pragma unroll
    for (int sk = 0; sk < 8; sk++)
      s += P2[((size_t)sk * 2048 + m0 + mi) * 256 + n];
    T1s[mi][n] = s * dr[m0 + mi];
  }
  __syncthreads();
  // phase 2: hid[m][j] = T1[m][:] @ Wl2[:,j] + bl2[j]
  const int j = tid & 63, mg = tid >> 6;  // mg covers rows mg*2 + {0,1}
  float h0 = bl2[j], h1 = h0;
  for (int n = 0; n < 256; n++) {
    float w = Wl2[(size_t)n * 64 + j];
    h0 = fmaf(T1s[mg * 2 + 0][n], w, h0);
    h1 = fmaf(T1s[mg * 2 + 1][n], w, h1);
  }
  hid[(size_t)(m0 + mg * 2 + 0) * 64 + j] = h0;
  hid[(size_t)(m0 + mg * 2 + 1) * 64 + j] = h1;
  hidS[mg * 2 + 0][j] = h0;
  hidS[mg * 2 + 1][j] = h1;
  __syncthreads();
  // phase 3: HW[m][c] = dc[m] * hid[m][:] @ Wg2[:,c]
  if (tid < 32) {
    const int r = tid >> 2, c = tid & 3;
    float s = 0.f;
#pragma unroll
    for (int jj = 0; jj < 64; jj++) s = fmaf(hidS[r][jj], Wg2[jj * 4 + c], s);
    HW[(size_t)(m0 + r) * 4 + c] = s * dc[m0 + r];
  }
}

// ---------------- out[i,:] = dr[i] * (Abf[i,:] @ HW) -------------------------
__global__ void __launch_bounds__(256) out_kernel(
    const unsigned short* __restrict__ Abf, const float* __restrict__ HW,
    const float* __restrict__ dr, float* __restrict__ outp) {
  const int i = blockIdx.x, tid = threadIdx.x;
  const ushort8v a8 = ((const ushort8v*)(Abf + (size_t)i * NN))[tid];
  const float4* hw4 = (const float4*)HW;
  const int j0 = tid * 8;
  float ax = 0.f, ay = 0.f, az = 0.f, aw = 0.f;
#pragma unroll
  for (int e = 0; e < 8; e++) {
    float a = b2f(a8[e]);
    float4 h = hw4[j0 + e];
    ax = fmaf(a, h.x, ax);
    ay = fmaf(a, h.y, ay);
    az = fmaf(a, h.z, az);
    aw = fmaf(a, h.w, aw);
  }
#pragma unroll
  for (int off = 32; off > 0; off >>= 1) {
    ax += __shfl_down(ax, off);
    ay += __shfl_down(ay, off);
    az += __shfl_down(az, off);
    aw += __shfl_down(aw, off);
  }
  __shared__ float wsum[4][4];
  const int w = tid >> 6;
  if ((tid & 63) == 0) {
    wsum[w][0] = ax; wsum[w][1] = ay; wsum[w][2] = az; wsum[w][3] = aw;
  }
  __syncthreads();
  if (tid < 4)
    outp[(size_t)i * 4 + tid] =
        dr[i] * (wsum[0][tid] + wsum[1][tid] + wsum[2][tid] + wsum[3][tid]);
}

extern "C" void kernel_launch(void* const* d_in, const int* in_sizes, int n_in,
                              void* d_out, int out_size, void* d_ws, size_t ws_size,
                              hipStream_t stream) {
  const float* x    = (const float*)d_in[0];
  const float* adj  = (const float*)d_in[1];
  const float* xdeg = (const float*)d_in[2];
  const float* ydeg = (const float*)d_in[3];
  const float* Wm1  = (const float*)d_in[4];
  const float* bm1  = (const float*)d_in[5];
  const float* Wm2  = (const float*)d_in[6];
  const float* bm2  = (const float*)d_in[7];
  const float* Wg1  = (const float*)d_in[8];
  const float* Wl2  = (const float*)d_in[9];
  const float* bl2  = (const float*)d_in[10];
  const float* Wg2  = (const float*)d_in[11];

  char* ws = (char*)d_ws;
  unsigned short* Abf  = (unsigned short*)(ws);               // 8 MiB [2048][2048]
  unsigned short* XWT  = (unsigned short*)(ws + 8388608);     // 1 MiB [256][2048]
  float* P     = (float*)(ws + 9437184);                      // 16 MiB split-K partials
  float* part  = (float*)(ws + 26214400);                     // 2 MiB [256][2048]
  unsigned short* xb   = (unsigned short*)(ws + 28311552);    // 4 MiB x bf16
  unsigned short* Wg1T = (unsigned short*)(ws + 32505856);    // 0.5 MiB Wg1^T bf16
  float* dr    = (float*)(ws + 33030144);
  float* dc    = (float*)(ws + 33038336);
  float* HW    = (float*)(ws + 33046528);                     // 32 KiB

  float* outp = (float*)d_out;             // output 0: [2048,4]
  float* hid  = (float*)d_out + 2048 * 4;  // output 1: [2048,64]

  edge_kernel<<<NN, 256, 0, stream>>>(adj, xdeg, ydeg, Wm1, bm1, Wm2, bm2, Abf, dr);
  // colsum (256 blk) + x cast (1024 blk) + Wg1 transpose (128 blk), one dispatch
  aux_kernel<<<1408, 256, 0, stream>>>(Abf, x, Wg1, part, xb, Wg1T);
  dc_kernel<<<64, 256, 0, stream>>>(part, dc);
  // GEMM1: P[sk][i][j] partial of Wg1T @ xb^T  (M=256, N=2048, K=1024, SK=8)
  gemm_splitk_kernel<<<dim3(2048 / 128, 256 / 64, 8), 256, 0, stream>>>(
      Wg1T, xb, P, 256, 2048, 1024, 128);
  reduce_xwt_kernel<<<256, 256, 0, stream>>>(P, dc, XWT);
  // GEMM2: P[sk][m][n] partial of Abf @ XWT^T  (M=2048, N=256, K=2048, SK=8)
  gemm_splitk_kernel<<<dim3(256 / 128, 2048 / 64, 8), 256, 0, stream>>>(
      Abf, XWT, P, 2048, 256, 2048, 256);
  tail_kernel<<<2048 / 8, 256, 0, stream>>>(P, dr, dc, Wl2, bl2, Wg2, hid, HW);
  out_kernel<<<NN, 256, 0, stream>>>(Abf, HW, dr, outp);
}